// Round 1
// baseline (140.222 us; speedup 1.0000x reference)
//
#include <hip/hip_runtime.h>

typedef __bf16 bf16x4 __attribute__((ext_vector_type(4)));
typedef __bf16 bf16x8 __attribute__((ext_vector_type(8)));
typedef float  f32x4  __attribute__((ext_vector_type(4)));

constexpr int S   = 200;   // sequence length
constexpr int SP  = 208;   // padded to 13*16
constexpr int D   = 128;   // embedding dim
constexpr int NTI = 13;    // 16-row tiles per dim
constexpr int ROWB = 256;  // bytes per LDS row (128 bf16)

constexpr int OFF_I   = SP * ROWB;          // 53248
constexpr int OFF_CU  = 2 * SP * ROWB;      // 106496
constexpr int OFF_CI  = OFF_CU + SP * 4;
constexpr int OFF_WU  = OFF_CI + SP * 4;
constexpr int OFF_WI  = OFF_WU + SP * 4;
constexpr int OFF_RED = OFF_WI + SP * 4;
constexpr int SMEM_BYTES = OFF_RED + 64;    // 109888

__device__ __forceinline__ float fast_tanh(float x) {
    // tanh(x) = 1 - 2/(e^{2x}+1); |x| ~ 5e-3 here, abs err ~2e-7
    float e = __expf(2.0f * x);
    return 1.0f - 2.0f * __builtin_amdgcn_rcpf(e + 1.0f);
}

__global__ __launch_bounds__(256) void deepred_kernel(
    const int* __restrict__ user_nh, const float* __restrict__ user_mask,
    const int* __restrict__ item_nh, const float* __restrict__ item_mask,
    const float* __restrict__ emb, float* __restrict__ out, int B)
{
    extern __shared__ char smem[];
    float* coefU = (float*)(smem + OFF_CU);
    float* coefI = (float*)(smem + OFF_CI);
    float* wU    = (float*)(smem + OFF_WU);
    float* wI    = (float*)(smem + OFF_WI);
    float* red   = (float*)(smem + OFF_RED);

    const int b    = blockIdx.x;
    const int tid  = threadIdx.x;
    const int lane = tid & 63;
    const int wid  = tid >> 6;

    if (tid < SP) coefI[tid] = 0.0f;   // atomic accumulator; coefU fully overwritten later

    // ---- stage U and I into LDS as bf16, XOR-swizzled rows ----
    // thread t owns column-chunk c4 = t&31 of rows r0+8j, r0 = t>>5
    {
        const float4* embv = (const float4*)emb;
        const int c4 = tid & 31, r0 = tid >> 5;
        for (int m = 0; m < 2; ++m) {
            const int* __restrict__ nh = m ? item_nh : user_nh;
            char* dst = (char*)smem + (m ? OFF_I : 0);
            int idxs[26];
            #pragma unroll
            for (int j = 0; j < 25; ++j) idxs[j] = nh[b * S + r0 + 8 * j]; // rows <200 always
            idxs[25] = 0;                                                  // padded rows 200..207
            #pragma unroll 5
            for (int j = 0; j < 26; ++j) {
                int row = r0 + 8 * j;
                int idx = idxs[j];
                float4 v = make_float4(0.f, 0.f, 0.f, 0.f);
                if (idx != 0) v = embv[(size_t)idx * 32 + c4];   // padding_idx=0 -> zero row
                bf16x4 h = { (__bf16)v.x, (__bf16)v.y, (__bf16)v.z, (__bf16)v.w };
                int off = row * ROWB + ((c4 * 8) ^ ((row & 7) << 4));
                *(bf16x4*)(dst + off) = h;
            }
        }
    }
    __syncthreads();

    // ---- align = tanh(U * I^T), accumulate row means (coefU) and col means (coefI) ----
    {
        const int lr = lane & 15;   // row-in-tile (A) / col-in-tile (B,C)
        const int lk = lane >> 4;   // k-group; C rows lk*4+r
        const char* ubase = (const char*)smem;
        const char* ibase = (const char*)smem + OFF_I;

        for (int u = 0; u < 2; ++u) {
            const int ti0 = wid + u * 8;            // 0..3, 8..11
            const int ti1 = ti0 + 4;                // 4..7, 12..15
            const bool two = (ti1 < NTI);
            const int r0 = ti0 * 16 + lr;
            const int r1 = two ? ti1 * 16 + lr : r0;

            bf16x8 a0[4], a1[4];
            #pragma unroll
            for (int kk = 0; kk < 4; ++kk) {
                int c = kk * 64 + lk * 16;
                a0[kk] = *(const bf16x8*)(ubase + r0 * ROWB + (c ^ ((r0 & 7) << 4)));
                a1[kk] = *(const bf16x8*)(ubase + r1 * ROWB + (c ^ ((r1 & 7) << 4)));
            }

            float rs0[4] = {0.f, 0.f, 0.f, 0.f};
            float rs1[4] = {0.f, 0.f, 0.f, 0.f};

            for (int tj = 0; tj < NTI; ++tj) {
                const int cr = tj * 16 + lr;
                bf16x8 bb[4];
                #pragma unroll
                for (int kk = 0; kk < 4; ++kk) {
                    int c = kk * 64 + lk * 16;
                    bb[kk] = *(const bf16x8*)(ibase + cr * ROWB + (c ^ ((cr & 7) << 4)));
                }
                f32x4 acc0 = {0.f, 0.f, 0.f, 0.f};
                f32x4 acc1 = {0.f, 0.f, 0.f, 0.f};
                #pragma unroll
                for (int kk = 0; kk < 4; ++kk) {
                    acc0 = __builtin_amdgcn_mfma_f32_16x16x32_bf16(a0[kk], bb[kk], acc0, 0, 0, 0);
                    acc1 = __builtin_amdgcn_mfma_f32_16x16x32_bf16(a1[kk], bb[kk], acc1, 0, 0, 0);
                }
                float cp = 0.f;
                #pragma unroll
                for (int r = 0; r < 4; ++r) {
                    float t0 = fast_tanh(acc0[r]);
                    rs0[r] += t0; cp += t0;
                    float t1 = fast_tanh(acc1[r]);
                    if (two) { rs1[r] += t1; cp += t1; }
                }
                // column partial: rows of this lane's lk-group (both strips) for col cr
                cp += __shfl_xor(cp, 16);
                cp += __shfl_xor(cp, 32);
                if (lane < 16) atomicAdd(&coefI[tj * 16 + lane], cp);
            }

            // row sums: reduce across the 16 lr lanes; strips are wave-exclusive -> plain store
            #pragma unroll
            for (int r = 0; r < 4; ++r) {
                float s0 = rs0[r], s1 = rs1[r];
                s0 += __shfl_xor(s0, 1); s0 += __shfl_xor(s0, 2);
                s0 += __shfl_xor(s0, 4); s0 += __shfl_xor(s0, 8);
                s1 += __shfl_xor(s1, 1); s1 += __shfl_xor(s1, 2);
                s1 += __shfl_xor(s1, 4); s1 += __shfl_xor(s1, 8);
                if (lr == 0) {
                    coefU[ti0 * 16 + lk * 4 + r] = s0;
                    if (two) coefU[ti1 * 16 + lk * 4 + r] = s1;
                }
            }
        }
    }
    __syncthreads();

    // ---- softmax over S for user and item coefs (sums -> /S, + additive mask) ----
    {
        float vu = -3.0e38f, vi = -3.0e38f;
        if (tid < S) {
            vu = coefU[tid] * (1.0f / S) + user_mask[b * S + tid];
            vi = coefI[tid] * (1.0f / S) + item_mask[b * S + tid];
        }
        float mu = vu, mi = vi;
        #pragma unroll
        for (int o = 32; o >= 1; o >>= 1) {
            mu = fmaxf(mu, __shfl_xor(mu, o));
            mi = fmaxf(mi, __shfl_xor(mi, o));
        }
        if (lane == 0) { red[wid] = mu; red[4 + wid] = mi; }
        __syncthreads();
        mu = fmaxf(fmaxf(red[0], red[1]), fmaxf(red[2], red[3]));
        mi = fmaxf(fmaxf(red[4], red[5]), fmaxf(red[6], red[7]));
        float eu = (tid < S) ? __expf(vu - mu) : 0.f;
        float ei = (tid < S) ? __expf(vi - mi) : 0.f;
        float su = eu, si = ei;
        #pragma unroll
        for (int o = 32; o >= 1; o >>= 1) {
            su += __shfl_xor(su, o);
            si += __shfl_xor(si, o);
        }
        if (lane == 0) { red[8 + wid] = su; red[12 + wid] = si; }
        __syncthreads();
        su = red[8] + red[9] + red[10] + red[11];
        si = red[12] + red[13] + red[14] + red[15];
        if (tid < SP) {
            wU[tid] = (tid < S) ? eu / su : 0.f;
            wI[tid] = (tid < S) ? ei / si : 0.f;
        }
    }
    __syncthreads();

    // ---- reps: out[0][b][d] = sum_s wU[s]*U[s][d]; out[1][b][d] = sum_s wI[s]*I[s][d] ----
    {
        const int d = tid & 127;
        const char* base = (const char*)smem + ((tid < 128) ? 0 : OFF_I);
        const float* w = (tid < 128) ? wU : wI;
        float acc = 0.f;
        #pragma unroll 8
        for (int s = 0; s < S; ++s) {
            int off = s * ROWB + ((d * 2) ^ ((s & 7) << 4));
            acc += w[s] * (float)(*(const __bf16*)(base + off));
        }
        out[((tid < 128) ? 0 : (size_t)B * D) + (size_t)b * D + d] = acc;
    }
}

extern "C" void kernel_launch(void* const* d_in, const int* in_sizes, int n_in,
                              void* d_out, int out_size, void* d_ws, size_t ws_size,
                              hipStream_t stream) {
    const int*   user_nh   = (const int*)d_in[1];
    const float* user_mask = (const float*)d_in[2];
    const int*   item_nh   = (const int*)d_in[4];
    const float* item_mask = (const float*)d_in[5];
    const float* emb       = (const float*)d_in[6];
    float* out = (float*)d_out;
    const int B = in_sizes[0];

    // >64KB dynamic LDS: opt in (ignore failure; gfx950 supports 160KB/WG)
    (void)hipFuncSetAttribute((const void*)deepred_kernel,
                              hipFuncAttributeMaxDynamicSharedMemorySize, SMEM_BYTES);

    deepred_kernel<<<dim3(B), dim3(256), SMEM_BYTES, stream>>>(
        user_nh, user_mask, item_nh, item_mask, emb, out, B);
}

// Round 2
// 71.757 us; speedup vs baseline: 1.9541x; 1.9541x over previous
//
#include <hip/hip_runtime.h>

typedef __bf16 bf16x4 __attribute__((ext_vector_type(4)));
typedef __bf16 bf16x8 __attribute__((ext_vector_type(8)));
typedef float  f32x4  __attribute__((ext_vector_type(4)));

constexpr int S    = 200;   // sequence length
constexpr int SP   = 208;   // padded to 13*16
constexpr int D    = 128;   // embedding dim
constexpr int NTI  = 13;    // 16-row tiles
constexpr int ROWB = 256;   // bytes per LDS row (128 bf16)

// single shared tile buffer: holds U during fragment caching, then I
constexpr int OFF_CU  = SP * ROWB;           // 53248
constexpr int OFF_CI  = OFF_CU + SP * 4;
constexpr int OFF_WU  = OFF_CI + SP * 4;
constexpr int OFF_WI  = OFF_WU + SP * 4;
constexpr int OFF_RU  = OFF_WI + SP * 4;     // repU: 128 f32
constexpr int OFF_RI  = OFF_RU + 128 * 4;    // repI: 128 f32
constexpr int OFF_RED = OFF_RI + 128 * 4;    // 16 f32
constexpr int SMEM_BYTES = OFF_RED + 64;     // 57664 B -> 2 WG/CU

__device__ __forceinline__ float fast_tanh(float x) {
    float e = __expf(2.0f * x);
    return 1.0f - 2.0f * __builtin_amdgcn_rcpf(e + 1.0f);
}

__global__ __launch_bounds__(256, 2) void deepred_kernel(
    const int* __restrict__ user_nh, const float* __restrict__ user_mask,
    const int* __restrict__ item_nh, const float* __restrict__ item_mask,
    const float* __restrict__ emb, float* __restrict__ out, int B)
{
    __shared__ __align__(16) char smem[SMEM_BYTES];
    float* coefU = (float*)(smem + OFF_CU);
    float* coefI = (float*)(smem + OFF_CI);
    float* wU    = (float*)(smem + OFF_WU);
    float* wI    = (float*)(smem + OFF_WI);
    float* repU  = (float*)(smem + OFF_RU);
    float* repI  = (float*)(smem + OFF_RI);
    float* red   = (float*)(smem + OFF_RED);

    const int b    = blockIdx.x;
    const int tid  = threadIdx.x;
    const int lane = tid & 63;
    const int wid  = tid >> 6;

    if (tid < SP) coefI[tid] = 0.0f;
    if (tid < 128) repU[tid] = 0.0f;
    else if (tid < 256) repI[tid - 128] = 0.0f;

    const float4* embv = (const float4*)emb;
    const int c4 = tid & 31;   // 16B chunk within row
    const int r0 = tid >> 5;   // 0..7; rows r0 + 8j

    // ---- stage U -> LDS tile (bf16, XOR-swizzled rows) ----
    {
        float4 uv[26];
        int umask = 0;
        #pragma unroll
        for (int j = 0; j < 26; ++j) {
            int row = r0 + 8 * j;
            int idx = (row < S) ? user_nh[b * S + row] : 0;
            uv[j] = embv[(size_t)idx * 32 + c4];     // idx 0 row loaded then masked
            if (idx != 0) umask |= 1 << j;
        }
        #pragma unroll
        for (int j = 0; j < 26; ++j) {
            int row = r0 + 8 * j;
            float4 v = (umask >> j & 1) ? uv[j] : make_float4(0.f, 0.f, 0.f, 0.f);
            bf16x4 h = { (__bf16)v.x, (__bf16)v.y, (__bf16)v.z, (__bf16)v.w };
            *(bf16x4*)(smem + row * ROWB + ((c4 * 8) ^ ((row & 7) << 4))) = h;
        }
    }

    // ---- issue I gather loads now (latency hides under fragment reads) ----
    float4 iv[26];
    int imask = 0;
    #pragma unroll
    for (int j = 0; j < 26; ++j) {
        int row = r0 + 8 * j;
        int idx = (row < S) ? item_nh[b * S + row] : 0;
        iv[j] = embv[(size_t)idx * 32 + c4];
        if (idx != 0) imask |= 1 << j;
    }
    __syncthreads();

    // ---- cache all A-fragments for this wave's strips in registers ----
    const int lr = lane & 15;   // A-row / B-col within tile
    const int lk = lane >> 4;   // k-group
    int tis[4];
    bf16x8 afr[4][4];
    #pragma unroll
    for (int u = 0; u < 4; ++u) {
        int ti = wid + 4 * u;
        tis[u] = ti;
        if (ti < NTI) {
            int ra = ti * 16 + lr;
            #pragma unroll
            for (int kk = 0; kk < 4; ++kk)
                afr[u][kk] = *(const bf16x8*)(smem + ra * ROWB +
                                              ((kk * 64 + lk * 16) ^ ((ra & 7) << 4)));
        }
    }
    __syncthreads();

    // ---- overwrite tile with I ----
    #pragma unroll
    for (int j = 0; j < 26; ++j) {
        int row = r0 + 8 * j;
        float4 v = (imask >> j & 1) ? iv[j] : make_float4(0.f, 0.f, 0.f, 0.f);
        bf16x4 h = { (__bf16)v.x, (__bf16)v.y, (__bf16)v.z, (__bf16)v.w };
        *(bf16x4*)(smem + row * ROWB + ((c4 * 8) ^ ((row & 7) << 4))) = h;
    }
    __syncthreads();

    // ---- align = tanh(U I^T): row sums (coefU) + col sums (coefI) ----
    {
        float rs[4][4] = {};
        for (int tj = 0; tj < NTI; ++tj) {
            const int cr = tj * 16 + lr;
            bf16x8 bb[4];
            #pragma unroll
            for (int kk = 0; kk < 4; ++kk)
                bb[kk] = *(const bf16x8*)(smem + cr * ROWB +
                                          ((kk * 64 + lk * 16) ^ ((cr & 7) << 4)));
            float cp = 0.f;
            #pragma unroll
            for (int u = 0; u < 4; ++u) {
                if (tis[u] < NTI) {   // wave-uniform
                    f32x4 acc = {0.f, 0.f, 0.f, 0.f};
                    #pragma unroll
                    for (int kk = 0; kk < 4; ++kk)
                        acc = __builtin_amdgcn_mfma_f32_16x16x32_bf16(afr[u][kk], bb[kk], acc, 0, 0, 0);
                    #pragma unroll
                    for (int r = 0; r < 4; ++r) {
                        float t = fast_tanh(acc[r]);
                        rs[u][r] += t;
                        cp += t;
                    }
                }
            }
            cp += __shfl_xor(cp, 16);
            cp += __shfl_xor(cp, 32);
            if (lane < 16) atomicAdd(&coefI[tj * 16 + lane], cp);
        }
        #pragma unroll
        for (int u = 0; u < 4; ++u) {
            if (tis[u] < NTI) {
                #pragma unroll
                for (int r = 0; r < 4; ++r) {
                    float s = rs[u][r];
                    s += __shfl_xor(s, 1); s += __shfl_xor(s, 2);
                    s += __shfl_xor(s, 4); s += __shfl_xor(s, 8);
                    if (lr == 0) coefU[tis[u] * 16 + lk * 4 + r] = s;
                }
            }
        }
    }
    __syncthreads();

    // ---- softmax over S (sum -> /S, + additive mask) ----
    {
        float vu = -3.0e38f, vi = -3.0e38f;
        if (tid < S) {
            vu = coefU[tid] * (1.0f / S) + user_mask[b * S + tid];
            vi = coefI[tid] * (1.0f / S) + item_mask[b * S + tid];
        }
        float mu = vu, mi = vi;
        #pragma unroll
        for (int o = 32; o >= 1; o >>= 1) {
            mu = fmaxf(mu, __shfl_xor(mu, o));
            mi = fmaxf(mi, __shfl_xor(mi, o));
        }
        if (lane == 0) { red[wid] = mu; red[4 + wid] = mi; }
        __syncthreads();
        mu = fmaxf(fmaxf(red[0], red[1]), fmaxf(red[2], red[3]));
        mi = fmaxf(fmaxf(red[4], red[5]), fmaxf(red[6], red[7]));
        float eu = (tid < S) ? __expf(vu - mu) : 0.f;
        float ei = (tid < S) ? __expf(vi - mi) : 0.f;
        float su = eu, si = ei;
        #pragma unroll
        for (int o = 32; o >= 1; o >>= 1) {
            su += __shfl_xor(su, o);
            si += __shfl_xor(si, o);
        }
        if (lane == 0) { red[8 + wid] = su; red[12 + wid] = si; }
        __syncthreads();
        su = red[8] + red[9] + red[10] + red[11];
        si = red[12] + red[13] + red[14] + red[15];
        if (tid < SP) {
            wU[tid] = (tid < S) ? eu / su : 0.f;
            wI[tid] = (tid < S) ? ei / si : 0.f;
        }
    }
    __syncthreads();

    // ---- user_rep from register A-fragments: repU[d] = sum_s wU[s]*U[s][d] ----
    {
        float racc[32];
        #pragma unroll
        for (int i = 0; i < 32; ++i) racc[i] = 0.f;
        #pragma unroll
        for (int u = 0; u < 4; ++u) {
            if (tis[u] < NTI) {
                float w = wU[tis[u] * 16 + lr];
                #pragma unroll
                for (int kk = 0; kk < 4; ++kk)
                    #pragma unroll
                    for (int j = 0; j < 8; ++j)
                        racc[kk * 8 + j] += w * (float)afr[u][kk][j];
            }
        }
        #pragma unroll
        for (int i = 0; i < 32; ++i) {
            float v = racc[i];
            v += __shfl_xor(v, 1); v += __shfl_xor(v, 2);
            v += __shfl_xor(v, 4); v += __shfl_xor(v, 8);
            racc[i] = v;
        }
        if (lr == 0) {
            #pragma unroll
            for (int kk = 0; kk < 4; ++kk)
                #pragma unroll
                for (int j = 0; j < 8; ++j)
                    atomicAdd(&repU[kk * 32 + lk * 8 + j], racc[kk * 8 + j]);
        }
    }
    __syncthreads();

    // ---- item_rep from LDS I tile ----
    {
        const int d = tid & 127, g = tid >> 7;   // 2 groups x 100 rows
        float acc = 0.f;
        #pragma unroll 4
        for (int s = g * 100; s < (g + 1) * 100; ++s)
            acc += wI[s] * (float)(*(const __bf16*)(smem + s * ROWB +
                                                    ((d * 2) ^ ((s & 7) << 4))));
        atomicAdd(&repI[d], acc);
    }
    __syncthreads();

    if (tid < 128) out[(size_t)b * D + tid] = repU[tid];
    else if (tid < 256) out[(size_t)B * D + (size_t)b * D + (tid - 128)] = repI[tid - 128];
}

extern "C" void kernel_launch(void* const* d_in, const int* in_sizes, int n_in,
                              void* d_out, int out_size, void* d_ws, size_t ws_size,
                              hipStream_t stream) {
    const int*   user_nh   = (const int*)d_in[1];
    const float* user_mask = (const float*)d_in[2];
    const int*   item_nh   = (const int*)d_in[4];
    const float* item_mask = (const float*)d_in[5];
    const float* emb       = (const float*)d_in[6];
    float* out = (float*)d_out;
    const int B = in_sizes[0];

    deepred_kernel<<<dim3(B), dim3(256), 0, stream>>>(
        user_nh, user_mask, item_nh, item_mask, emb, out, B);
}